// Round 5
// baseline (111.163 us; speedup 1.0000x reference)
//
#include <hip/hip_runtime.h>
#include <hip/hip_bf16.h>

// Positional encoder: per input element e, 20 outputs [sin(x*2^0..9), cos(x*2^0..9)].
// Memory-bound: 24 MB read + 480 MB write. One thread per OUTPUT float4 (slot quad
// q=0..4 of element e) => perfectly coalesced dwordx4 stores. Persistent grid with
// total threads T divisible by 5 => q loop-invariant, slot->(scale,offset) hoisted.
// cos(2*pi*r) = sin(2*pi*(r+0.25)); 0.25 and 2^d scaling exact in fp32.
// R4: unroll x2 (quads g and g+T per iteration) + plain stores (fillBuffer-proven
// full-line write-combining path) instead of nontemporal.

#define ENC_BLOCK 256
#define ENC_GRID  1280              // T = 327,680 threads, divisible by 5

__global__ __launch_bounds__(ENC_BLOCK)
void Encoder_65077344469353_kernel(const float* __restrict__ x,
                                   float* __restrict__ out,
                                   int n_elem) {
    typedef float f4 __attribute__((ext_vector_type(4)));
    const unsigned nq    = (unsigned)n_elem * 5u;      // 30,000,000 quads
    const unsigned T     = ENC_BLOCK * ENC_GRID;       // 327,680
    const unsigned estep = T / 5u;                     // 65,536 elements per sweep

    unsigned g = blockIdx.x * ENC_BLOCK + threadIdx.x;
    const unsigned q = g % 5u;                         // loop-invariant quad id
    unsigned e = g / 5u;

    // Hoisted: out[i] = sin(2*pi * fract(x*sc[i] + off[i]))
    float sc[4], off[4];
    #pragma unroll
    for (int i = 0; i < 4; ++i) {
        const int s   = (int)(q * 4u) + i;             // slot 0..19
        const int isc = (s >= 10) ? 1 : 0;             // cos half
        const int d   = s - 10 * isc;                  // exponent 0..9
        sc[i]  = __uint_as_float((unsigned)(127 + d) << 23) * 0.15915494309189535f;
        off[i] = isc ? 0.25f : 0.0f;
    }

    f4* __restrict__ out4 = (f4*)out;

    #define ENC_QUAD(xv, dst)                                                          \
        {                                                                              \
            f4 o_;                                                                     \
            o_.x = __builtin_amdgcn_sinf(__builtin_amdgcn_fractf(__builtin_fmaf(xv, sc[0], off[0]))); \
            o_.y = __builtin_amdgcn_sinf(__builtin_amdgcn_fractf(__builtin_fmaf(xv, sc[1], off[1]))); \
            o_.z = __builtin_amdgcn_sinf(__builtin_amdgcn_fractf(__builtin_fmaf(xv, sc[2], off[2]))); \
            o_.w = __builtin_amdgcn_sinf(__builtin_amdgcn_fractf(__builtin_fmaf(xv, sc[3], off[3]))); \
            out4[dst] = o_;                                                            \
        }

    // Main unroll-2 loop: two independent loads + stores in flight per thread.
    for (; g + T < nq; g += 2 * T, e += 2 * estep) {
        const float xv0 = x[e];
        const float xv1 = x[e + estep];
        ENC_QUAD(xv0, g);
        ENC_QUAD(xv1, g + T);
    }
    if (g < nq) {
        const float xv0 = x[e];
        ENC_QUAD(xv0, g);
    }
    #undef ENC_QUAD
}

extern "C" void kernel_launch(void* const* d_in, const int* in_sizes, int n_in,
                              void* d_out, int out_size, void* d_ws, size_t ws_size,
                              hipStream_t stream) {
    const float* x = (const float*)d_in[0];
    float* out = (float*)d_out;
    const int n_elem = in_sizes[0];                    // N*3 = 6,000,000
    Encoder_65077344469353_kernel<<<dim3(ENC_GRID), dim3(ENC_BLOCK), 0, stream>>>(
        x, out, n_elem);
}